// Round 2
// baseline (101.007 us; speedup 1.0000x reference)
//
#include <hip/hip_runtime.h>
#include <math.h>

// B=8, N=128, H2=800, FD=500, P=100
#define FD 500
#define H2 800
#define NB 8
#define NN 128
#define NR (NB*NN)      // 1024 rows
#define NC (4*FD)       // 2000 combined feature cols (head, mod, sib, grd)

#define NEG_HUGE (-1.0e30f)   // stands in for -inf (ref-inf minus finite -> err=inf <= threshold=inf)

__device__ __forceinline__ float fast_tanh(float x) {
    // exact identity tanh(x) = 1 - 2/(exp(2x)+1)
    float e = __expf(2.0f * x);
    return 1.0f - 2.0f / (e + 1.0f);
}

// ---------------------------------------------------------------------------
// Kernel 1: selector vectors (8 x 500, stride 512) and 3 scalar constants
//  sel0=vg(grd->gk) sel1=vgh(head->gj) sel2=vgm(mod->gi)
//  sel3=vsh(head->sk) sel4=vss(sib->sj) sel5=vsm(mod->si)
//  sel6=vrh(head->r0) sel7=vrm(mod->ri)
//  consts: {c_g, c_s, c_r}
// ---------------------------------------------------------------------------
__global__ void prep_kernel(const float* __restrict__ W_gp, const float* __restrict__ b_gp,
                            const float* __restrict__ W_sp, const float* __restrict__ b_sp,
                            const float* __restrict__ W_rp, const float* __restrict__ b_rp,
                            const float* __restrict__ w_go, const float* __restrict__ b_go,
                            const float* __restrict__ w_so, const float* __restrict__ b_so,
                            float* __restrict__ sel, float* __restrict__ consts) {
    int v = blockIdx.x;
    int f = threadIdx.x;
    const float* wvec; const float* mat; int cols; int off;
    if (v < 3)      { wvec = w_go; mat = W_gp; cols = 3*FD; off = v*FD; }
    else if (v < 6) { wvec = w_so; mat = W_sp; cols = 3*FD; off = (v-3)*FD; }
    else            { wvec = w_go; mat = W_rp; cols = 2*FD; off = (v-6)*FD; }
    if (f < FD) {
        float s = 0.f;
        #pragma unroll 4
        for (int p = 0; p < 100; ++p) s += wvec[p] * mat[p*cols + off + f];
        sel[v*512 + f] = s;
    }
    if (v == 0 && f >= FD && f < FD+3) {
        int which = f - FD;
        const float* bv; const float* wv; float badd;
        if (which == 0)      { bv = b_gp; wv = w_go; badd = b_go[0]; }
        else if (which == 1) { bv = b_sp; wv = w_so; badd = b_so[0]; }
        else                 { bv = b_rp; wv = w_go; badd = b_go[0]; }
        float s = badd;
        for (int p = 0; p < 100; ++p) s += bv[p] * wv[p];
        consts[which] = s;
    }
}

// ---------------------------------------------------------------------------
// Kernel 2: T[r][c] = tanh(A[r,:] . Wrow(c) + bias(c)),  r<1024, c<2000
//  BM=BN=64, KT=16, 256 threads, 4x4 register tile, transposed LDS tiles
// ---------------------------------------------------------------------------
#define BM 64
#define BN 64
#define KT 16

__global__ __launch_bounds__(256) void gemm_tanh_kernel(
        const float* __restrict__ A,
        const float* __restrict__ Wh, const float* __restrict__ bh,
        const float* __restrict__ Wm, const float* __restrict__ bm,
        const float* __restrict__ Ws, const float* __restrict__ bs,
        const float* __restrict__ Wg, const float* __restrict__ bg,
        float* __restrict__ T) {
    __shared__ float As[KT][BM];
    __shared__ float Bs[KT][BN];
    int tid = threadIdx.x;
    int c0 = blockIdx.x * BN;
    int r0 = blockIdx.y * BM;

    int lm = tid & 63;
    int lk = tid >> 6;     // 0..3

    const float* arow = A + (size_t)(r0 + lm) * H2;

    int c = c0 + lm; if (c >= NC) c = NC - 1;   // clamp (results discarded)
    int wt = c / FD, wf = c % FD;
    const float* wmat = (wt==0)?Wh:(wt==1)?Wm:(wt==2)?Ws:Wg;
    const float* wrow = wmat + (size_t)wf * H2;

    float acc[4][4];
    #pragma unroll
    for (int i=0;i<4;++i)
        #pragma unroll
        for (int j=0;j<4;++j) acc[i][j]=0.f;

    int tm = tid & 15;   // row sub-tile
    int tn = tid >> 4;   // col sub-tile

    float4 aReg = *(const float4*)(arow + lk*4);
    float4 wReg = *(const float4*)(wrow + lk*4);

    const int NT = H2 / KT;   // 50
    for (int kt = 0; kt < NT; ++kt) {
        __syncthreads();
        As[lk*4+0][lm] = aReg.x; As[lk*4+1][lm] = aReg.y;
        As[lk*4+2][lm] = aReg.z; As[lk*4+3][lm] = aReg.w;
        Bs[lk*4+0][lm] = wReg.x; Bs[lk*4+1][lm] = wReg.y;
        Bs[lk*4+2][lm] = wReg.z; Bs[lk*4+3][lm] = wReg.w;
        __syncthreads();
        if (kt+1 < NT) {
            aReg = *(const float4*)(arow + (kt+1)*KT + lk*4);
            wReg = *(const float4*)(wrow + (kt+1)*KT + lk*4);
        }
        #pragma unroll
        for (int k = 0; k < KT; ++k) {
            float4 a4 = *(const float4*)&As[k][tm*4];
            float4 b4 = *(const float4*)&Bs[k][tn*4];
            float av[4] = {a4.x,a4.y,a4.z,a4.w};
            float bv[4] = {b4.x,b4.y,b4.z,b4.w};
            #pragma unroll
            for (int i=0;i<4;++i)
                #pragma unroll
                for (int j=0;j<4;++j)
                    acc[i][j] += av[i]*bv[j];
        }
    }

    int cbase = c0 + tn*4;
    if (cbase < NC) {      // cbase%4==0 and NC%4==0 -> whole float4 valid
        float bias[4];
        #pragma unroll
        for (int j=0;j<4;++j) {
            int cc = cbase + j;
            int t2 = cc / FD, f2 = cc % FD;
            const float* bb = (t2==0)?bh:(t2==1)?bm:(t2==2)?bs:bg;
            bias[j] = bb[f2];
        }
        #pragma unroll
        for (int i=0;i<4;++i) {
            int r = r0 + tm*4 + i;
            float4 o;
            o.x = fast_tanh(acc[i][0] + bias[0]);
            o.y = fast_tanh(acc[i][1] + bias[1]);
            o.z = fast_tanh(acc[i][2] + bias[2]);
            o.w = fast_tanh(acc[i][3] + bias[3]);
            *(float4*)(T + (size_t)r*NC + cbase) = o;
        }
    }
}

// ---------------------------------------------------------------------------
// Kernel 3: per-row reduction of T against selectors ->
//  rowvals[r][8] = {gi, gj, gk, si, sj, sk, ri, r0h}
// ---------------------------------------------------------------------------
__global__ __launch_bounds__(256) void reduce_kernel(
        const float* __restrict__ T, const float* __restrict__ sel,
        float* __restrict__ rowvals) {
    int r = blockIdx.x;
    int tid = threadIdx.x;
    float p[8];
    #pragma unroll
    for (int q=0;q<8;++q) p[q]=0.f;
    const float* trow = T + (size_t)r * NC;
    for (int c = tid; c < NC; c += 256) {
        float y = trow[c];
        int t2 = c / FD, f2 = c % FD;
        if (t2 == 0) {              // head
            p[1] += y * sel[1*512 + f2];   // gj
            p[5] += y * sel[3*512 + f2];   // sk
            p[7] += y * sel[6*512 + f2];   // r0h
        } else if (t2 == 1) {       // mod
            p[0] += y * sel[2*512 + f2];   // gi
            p[3] += y * sel[5*512 + f2];   // si
            p[6] += y * sel[7*512 + f2];   // ri
        } else if (t2 == 2) {       // sib
            p[4] += y * sel[4*512 + f2];   // sj
        } else {                    // grd
            p[2] += y * sel[0*512 + f2];   // gk
        }
    }
    __shared__ float red[256][8];
    #pragma unroll
    for (int q=0;q<8;++q) red[tid][q] = p[q];
    __syncthreads();
    for (int s = 128; s > 0; s >>= 1) {
        if (tid < s) {
            #pragma unroll
            for (int q=0;q<8;++q) red[tid][q] += red[tid+s][q];
        }
        __syncthreads();
    }
    if (tid < 8) rowvals[(size_t)r*8 + tid] = red[0][tid];
}

// ---------------------------------------------------------------------------
// Kernel 4: fill both (B,N,N,N) outputs.
//  grand[b,i,k,j] = valid ? tanh(gi+gk+gj+c_g) : NEG_HUGE
//  sib  [b,i,k,j] = valid ? tanh(si+sk+sj+c_s) : 0
//  valid = (i!=0)&(i!=j)&(j!=k); grand[b,i>=1,0,0] = root
// ---------------------------------------------------------------------------
#define KSPLIT 2
__global__ __launch_bounds__(256) void fill_kernel(
        const float* __restrict__ rowvals, const float* __restrict__ consts,
        float* __restrict__ grand, float* __restrict__ sib) {
    int bi = blockIdx.x;          // b*128 + i
    int kz = blockIdx.y;
    int b = bi >> 7;
    int i = bi & 127;
    int tid = threadIdx.x;

    __shared__ float gks[128], gjs[128], sks[128], sjs[128];
    if (tid < 128) {
        const float* rv = rowvals + (size_t)(b*128 + tid)*8;
        gks[tid] = rv[2];
        gjs[tid] = rv[1];
        sks[tid] = rv[5];
        sjs[tid] = rv[4];
    }
    __syncthreads();

    const float* rvi = rowvals + (size_t)bi * 8;
    float gi = rvi[0], si = rvi[3];
    float c_g = consts[0], c_s = consts[1], c_r = consts[2];
    float r0 = rowvals[(size_t)(b*128)*8 + 7];
    float ri = rvi[6];
    float rootv = fast_tanh(r0 + ri + c_r);

    size_t base = (size_t)bi * (128*128);

    int j4 = (tid & 31) * 4;
    int klo = tid >> 5;                  // 0..7
    const int KROWS = 128 / KSPLIT;      // 64

    for (int it = 0; it < KROWS/8; ++it) {
        int k = kz*KROWS + it*8 + klo;
        float gk = gks[k], sk = sks[k];
        float4 go, so;
        #pragma unroll
        for (int jj = 0; jj < 4; ++jj) {
            int j = j4 + jj;
            bool valid = (i != 0) && (i != j) && (j != k);
            float g = valid ? fast_tanh(gi + gk + gjs[j] + c_g) : NEG_HUGE;
            float s = valid ? fast_tanh(si + sk + sjs[j] + c_s) : 0.0f;
            if (i != 0 && k == 0 && j == 0) g = rootv;
            (&go.x)[jj] = g;
            (&so.x)[jj] = s;
        }
        size_t off = base + (size_t)k*128 + j4;
        *(float4*)(grand + off) = go;
        *(float4*)(sib + off) = so;
    }
}

// ---------------------------------------------------------------------------
extern "C" void kernel_launch(void* const* d_in, const int* in_sizes, int n_in,
                              void* d_out, int out_size, void* d_ws, size_t ws_size,
                              hipStream_t stream) {
    const float* hidden = (const float*)d_in[0];
    const float* Wh  = (const float*)d_in[1];   const float* bh  = (const float*)d_in[2];
    const float* Wm  = (const float*)d_in[3];   const float* bm  = (const float*)d_in[4];
    const float* Ws_ = (const float*)d_in[5];   const float* bs  = (const float*)d_in[6];
    const float* Wg  = (const float*)d_in[7];   const float* bg  = (const float*)d_in[8];
    const float* W_gp = (const float*)d_in[9];  const float* b_gp = (const float*)d_in[10];
    const float* W_sp = (const float*)d_in[11]; const float* b_sp = (const float*)d_in[12];
    const float* W_rp = (const float*)d_in[13]; const float* b_rp = (const float*)d_in[14];
    const float* w_go = (const float*)d_in[15]; const float* b_go = (const float*)d_in[16];
    const float* w_so = (const float*)d_in[17]; const float* b_so = (const float*)d_in[18];

    float* out   = (float*)d_out;
    float* grand = out;                        // 16777216 floats
    float* sib   = out + (size_t)16777216;     // 16777216 floats

    // All scratch in d_ws (read-after-write within stream order only).
    float* T       = (float*)d_ws;             // 1024*2000 = 2048000 floats (8 MB)
    float* sel     = T + 2048000;              // 8*512 floats
    float* consts  = sel + 4096;               // 3 floats
    float* rowvals = consts + 16;              // 1024*8 floats
    // total: ~8.44 MB <= ws_size (assumed)

    prep_kernel<<<dim3(8), dim3(512), 0, stream>>>(W_gp, b_gp, W_sp, b_sp, W_rp, b_rp,
                                                   w_go, b_go, w_so, b_so, sel, consts);
    gemm_tanh_kernel<<<dim3(32,16), dim3(256), 0, stream>>>(hidden, Wh, bh, Wm, bm,
                                                            Ws_, bs, Wg, bg, T);
    reduce_kernel<<<dim3(NR), dim3(256), 0, stream>>>(T, sel, rowvals);
    fill_kernel<<<dim3(NR, KSPLIT), dim3(256), 0, stream>>>(rowvals, consts, grand, sib);
}